// Round 1
// baseline (193.431 us; speedup 1.0000x reference)
//
#include <hip/hip_runtime.h>
#include <hip/hip_bf16.h>
#include <stdint.h>

#define NN 4096
#define DD 256
#define TH 0.04f

typedef __attribute__((ext_vector_type(4))) float f32x4;
typedef __attribute__((ext_vector_type(8))) short s16x8;
typedef __attribute__((ext_vector_type(4))) unsigned short u16x4;

__device__ __forceinline__ unsigned short f2bf(float f) {
  union { float f; uint32_t u; } x; x.f = f;
  uint32_t u = x.u;
  return (unsigned short)((u + 0x7FFFu + ((u >> 16) & 1u)) >> 16);  // RNE
}
__device__ __forceinline__ float bf2f(unsigned short h) {
  union { uint32_t u; float f; } x; x.u = ((uint32_t)h) << 16;
  return x.f;
}

// ---- prep: W^T as bf16 (both layers) ------------------------------------
__global__ __launch_bounds__(256) void k_prep(const float* __restrict__ W1,
                                              const float* __restrict__ W2,
                                              unsigned short* __restrict__ WTb,
                                              unsigned short* __restrict__ W2Tb) {
  int idx = blockIdx.x * 256 + threadIdx.x;     // 65536
  int d = idx >> 8, k = idx & 255;
  WTb[idx]  = f2bf(W1[k * 256 + d]);
  W2Tb[idx] = f2bf(W2[k * 256 + d]);
}

// ---- one pass over A: bitmask + integer row/col counts (exact, deterministic)
__global__ __launch_bounds__(256) void k_deg(const float* __restrict__ A,
                                             uint64_t* __restrict__ bits,
                                             unsigned int* __restrict__ rowcnt,
                                             unsigned int* __restrict__ colcnt) {
  const int t = threadIdx.x;
  const int u0 = blockIdx.x * 16;
  unsigned int cs[16];
#pragma unroll
  for (int c = 0; c < 16; ++c) cs[c] = 0;
  for (int r = 0; r < 16; ++r) {
    const int u = u0 + r;
    const float* __restrict__ Arow = A + (size_t)u * NN;
    unsigned int rs = 0;
#pragma unroll
    for (int c = 0; c < 16; ++c) {
      int v = c * 256 + t;
      bool p = Arow[v] >= TH;
      unsigned long long bal = __ballot(p);
      if ((t & 63) == 0) bits[(size_t)u * 64 + (v >> 6)] = bal;
      cs[c] += p ? 1u : 0u;
      rs += (unsigned int)__popcll(bal);
    }
    if ((t & 63) == 0) atomicAdd(&rowcnt[u], rs);
  }
#pragma unroll
  for (int c = 0; c < 16; ++c) atomicAdd(&colcnt[c * 256 + t], cs[c]);
}

__global__ __launch_bounds__(256) void k_isqrt(const unsigned int* __restrict__ rowcnt,
                                               const unsigned int* __restrict__ colcnt,
                                               float* __restrict__ oi, float* __restrict__ ii) {
  int i = blockIdx.x * 256 + threadIdx.x;
  oi[i] = rsqrtf((float)(rowcnt[i] + 1u));   // +1 self loop; always >=1
  ii[i] = rsqrtf((float)(colcnt[i] + 1u));
}

// ---- hW = (H * oi[:,None]) @ W  -> hWb [u][d] bf16 and hWbT [d][u] bf16 --
__global__ __launch_bounds__(256) void k_hw(const float* __restrict__ H,
                                            const float* __restrict__ oi,
                                            const unsigned short* __restrict__ WTb,
                                            unsigned short* __restrict__ hWb,
                                            unsigned short* __restrict__ hWbT) {
  __shared__ unsigned short lt[64][260];
  const int t = threadIdx.x;
  const int lane = t & 63, w = t >> 6;
  const int l15 = lane & 15, l4 = lane >> 4;
  const int u0 = blockIdx.x * 64;
  const f32x4 z = {0.f, 0.f, 0.f, 0.f};
  f32x4 acc[4][4];
#pragma unroll
  for (int i = 0; i < 4; ++i)
#pragma unroll
    for (int j = 0; j < 4; ++j) acc[i][j] = z;
  float oiv[4];
#pragma unroll
  for (int i = 0; i < 4; ++i) oiv[i] = oi[u0 + i * 16 + l15];

  for (int ks = 0; ks < 8; ++ks) {
    const int k0 = ks * 32;
    s16x8 af[4];
#pragma unroll
    for (int i = 0; i < 4; ++i) {
      const f32x4* pa = reinterpret_cast<const f32x4*>(H + (size_t)(u0 + i * 16 + l15) * DD + k0 + l4 * 8);
      f32x4 a0 = pa[0], a1 = pa[1];
#pragma unroll
      for (int j = 0; j < 4; ++j) {
        af[i][j]     = (short)f2bf(a0[j] * oiv[i]);
        af[i][j + 4] = (short)f2bf(a1[j] * oiv[i]);
      }
    }
#pragma unroll
    for (int jn = 0; jn < 4; ++jn) {
      const int d = w * 64 + jn * 16 + l15;
      s16x8 bf = *reinterpret_cast<const s16x8*>(WTb + (size_t)d * DD + k0 + l4 * 8);
#pragma unroll
      for (int i = 0; i < 4; ++i)
        acc[i][jn] = __builtin_amdgcn_mfma_f32_16x16x32_bf16(af[i], bf, acc[i][jn], 0, 0, 0);
    }
  }
  // epilogue: hWb direct (coalesced-ish), hWbT via LDS transpose
#pragma unroll
  for (int i = 0; i < 4; ++i)
#pragma unroll
    for (int jn = 0; jn < 4; ++jn) {
      const int d = w * 64 + jn * 16 + l15;
#pragma unroll
      for (int r = 0; r < 4; ++r) {
        const int ul = i * 16 + l4 * 4 + r;      // C/D: row=(l>>4)*4+reg, col=l&15
        unsigned short hv = f2bf(acc[i][jn][r]);
        hWb[(size_t)(u0 + ul) * DD + d] = hv;
        lt[ul][d] = hv;
      }
    }
  __syncthreads();
#pragma unroll
  for (int c = 0; c < 8; ++c) {                  // thread t owns hWbT row d=t
    uint4 val;
    val.x = (uint32_t)lt[c*8+0][t] | ((uint32_t)lt[c*8+1][t] << 16);
    val.y = (uint32_t)lt[c*8+2][t] | ((uint32_t)lt[c*8+3][t] << 16);
    val.z = (uint32_t)lt[c*8+4][t] | ((uint32_t)lt[c*8+5][t] << 16);
    val.w = (uint32_t)lt[c*8+6][t] | ((uint32_t)lt[c*8+7][t] << 16);
    *reinterpret_cast<uint4*>(hWbT + (size_t)t * NN + u0 + c * 8) = val;
  }
}

// ---- partial[sk][v][d] = sum_{u in chunk} mask[u][v] * hW[u][d] ----------
// grid (64 v-tiles, 4 splitK); block 256 = 4 waves, each wave 64(v) x 64(d).
// No LDS, no barriers: bit-words + B-frags loaded from L2, depth-1 prefetch.
__global__ __launch_bounds__(256) void k_spmm(const uint64_t* __restrict__ bits,
                                              const unsigned short* __restrict__ hWbT,
                                              float* __restrict__ part) {
  const int t = threadIdx.x;
  const int lane = t & 63, w = t >> 6;
  const int l15 = lane & 15, l4 = lane >> 4;
  const int bv = blockIdx.x;          // word column == v-tile (64 v per word)
  const int sk = blockIdx.y;
  const int kbase = sk * 1024;
  const f32x4 z = {0.f, 0.f, 0.f, 0.f};
  f32x4 acc[4][4];
#pragma unroll
  for (int i = 0; i < 4; ++i)
#pragma unroll
    for (int j = 0; j < 4; ++j) acc[i][j] = z;

  uint2 wa[8]; s16x8 ba[4];
  uint2 wb[8]; s16x8 bb[4];

  auto loadw = [&](uint2* wv, s16x8* bv8, int k) {
#pragma unroll
    for (int j = 0; j < 8; ++j)
      wv[j] = *reinterpret_cast<const uint2*>(bits + (size_t)(k + l4 * 8 + j) * 64 + bv);
#pragma unroll
    for (int jn = 0; jn < 4; ++jn)
      bv8[jn] = *reinterpret_cast<const s16x8*>(hWbT + (size_t)(w * 64 + jn * 16 + l15) * NN + k + l4 * 8);
  };
  auto comp = [&](const uint2* wv, const s16x8* bv8) {
    s16x8 af[4];
#pragma unroll
    for (int i = 0; i < 4; ++i) {                // A-frag: m = i*16+l15, k = l4*8+j
      const int sh = (i & 1) * 16 + l15;         // bitpos = i*16+l15 (lo/hi word by i)
#pragma unroll
      for (int j = 0; j < 8; ++j) {
        uint32_t h = (i < 2) ? wv[j].x : wv[j].y;
        af[i][j] = (short)((((h >> sh) & 1u) != 0u) ? 0x3F80 : 0);
      }
    }
#pragma unroll
    for (int i = 0; i < 4; ++i)
#pragma unroll
      for (int jn = 0; jn < 4; ++jn)
        acc[i][jn] = __builtin_amdgcn_mfma_f32_16x16x32_bf16(af[i], bv8[jn], acc[i][jn], 0, 0, 0);
  };

  loadw(wa, ba, kbase);
#pragma unroll 1
  for (int it = 0; it < 16; ++it) {
    loadw(wb, bb, kbase + it * 64 + 32);
    comp(wa, ba);
    loadw(wa, ba, kbase + it * 64 + 64);   // last iter reads in-ws garbage, unused
    comp(wb, bb);
  }
  float* __restrict__ P = part + (size_t)sk * NN * DD;
#pragma unroll
  for (int i = 0; i < 4; ++i)
#pragma unroll
    for (int jn = 0; jn < 4; ++jn) {
      const int d = w * 64 + jn * 16 + l15;
#pragma unroll
      for (int r = 0; r < 4; ++r) {
        const int v = bv * 64 + i * 16 + l4 * 4 + r;
        P[(size_t)v * DD + d] = acc[i][jn][r];
      }
    }
}

// ---- combine: out = relu((sum_k partials + hW_self) * ii[v] + b[d]) ------
__global__ __launch_bounds__(256) void k_comb(const float* __restrict__ part,
                                              const unsigned short* __restrict__ hWb,
                                              const float* __restrict__ ii,
                                              const float* __restrict__ bias,
                                              float* __restrict__ out) {
  const int idx4 = blockIdx.x * 256 + threadIdx.x;   // 0..262143 (float4 units)
  const f32x4* p = reinterpret_cast<const f32x4*>(part);
  f32x4 s = p[idx4];
  s += p[idx4 + 262144];
  s += p[idx4 + 2 * 262144];
  s += p[idx4 + 3 * 262144];
  u16x4 hs = *reinterpret_cast<const u16x4*>(hWb + (size_t)idx4 * 4);
  const int v = idx4 >> 6;
  const int dbase = (idx4 & 63) * 4;
  const float iiv = ii[v];
  f32x4 o;
#pragma unroll
  for (int e = 0; e < 4; ++e) {
    float val = (s[e] + bf2f(hs[e])) * iiv + bias[dbase + e];
    o[e] = fmaxf(val, 0.f);
  }
  reinterpret_cast<f32x4*>(out)[idx4] = o;
}

extern "C" void kernel_launch(void* const* d_in, const int* in_sizes, int n_in,
                              void* d_out, int out_size, void* d_ws, size_t ws_size,
                              hipStream_t stream) {
  const float* A    = (const float*)d_in[0];
  const float* feat = (const float*)d_in[1];
  const float* W1   = (const float*)d_in[2];
  const float* b1   = (const float*)d_in[3];
  const float* W2   = (const float*)d_in[4];
  const float* b2   = (const float*)d_in[5];
  float* out = (float*)d_out;
  char* ws = (char*)d_ws;

  uint64_t*       bits   = (uint64_t*)ws;                       // 2 MiB
  unsigned short* hWbT   = (unsigned short*)(ws + (2u  << 20)); // 2 MiB
  unsigned short* hWb    = (unsigned short*)(ws + (4u  << 20)); // 2 MiB
  float*          part   = (float*)(ws + (6u  << 20));          // 16 MiB
  unsigned short* WTb    = (unsigned short*)(ws + (22u << 20));            // 128 KiB
  unsigned short* W2Tb   = (unsigned short*)(ws + (22u << 20) + (128u << 10));
  unsigned int*   rowcnt = (unsigned int*)(ws + (22u << 20) + (256u << 10));
  unsigned int*   colcnt = rowcnt + NN;
  float*          oi     = (float*)(colcnt + NN);
  float*          ii     = oi + NN;
  // total ws use ~22.3 MiB

  hipMemsetAsync(rowcnt, 0, 2 * NN * sizeof(unsigned int), stream);
  k_prep<<<256, 256, 0, stream>>>(W1, W2, WTb, W2Tb);
  k_deg<<<256, 256, 0, stream>>>(A, bits, rowcnt, colcnt);
  k_isqrt<<<16, 256, 0, stream>>>(rowcnt, colcnt, oi, ii);

  // layer 1
  k_hw<<<64, 256, 0, stream>>>(feat, oi, WTb, hWb, hWbT);
  k_spmm<<<dim3(64, 4), 256, 0, stream>>>(bits, hWbT, part);
  k_comb<<<1024, 256, 0, stream>>>(part, hWb, ii, b1, out);

  // layer 2 (input h1 = out[0:N*D], written fully by k_comb above)
  k_hw<<<64, 256, 0, stream>>>(out, oi, W2Tb, hWb, hWbT);
  k_spmm<<<dim3(64, 4), 256, 0, stream>>>(bits, hWbT, part);
  k_comb<<<1024, 256, 0, stream>>>(part, hWb, ii, b2, out + (size_t)NN * DD);
}

// Round 2
// 129.294 us; speedup vs baseline: 1.4961x; 1.4961x over previous
//
#include <hip/hip_runtime.h>
#include <hip/hip_bf16.h>
#include <stdint.h>

#define NN 4096
#define DD 256
#define TH 0.04f

typedef __attribute__((ext_vector_type(4))) float f32x4;
typedef __attribute__((ext_vector_type(8))) short s16x8;
typedef __attribute__((ext_vector_type(4))) unsigned short u16x4;

__device__ __forceinline__ unsigned short f2bf(float f) {
  union { float f; uint32_t u; } x; x.f = f;
  uint32_t u = x.u;
  return (unsigned short)((u + 0x7FFFu + ((u >> 16) & 1u)) >> 16);  // RNE
}
__device__ __forceinline__ float bf2f(unsigned short h) {
  union { uint32_t u; float f; } x; x.u = ((uint32_t)h) << 16;
  return x.f;
}

// ---- pass over A: build bitmask + per-block column partial counts --------
// 512 blocks x 8 rows. Thread t owns 16 contiguous columns [t*16, t*16+16).
// Its 16-bit mask stored at bits16[u*256+t] is bit-identical to the uint64
// word layout k_spmm consumes (little-endian). No ballots, no atomics.
__global__ __launch_bounds__(256) void k_deg(const float* __restrict__ A,
                                             unsigned short* __restrict__ bits16,
                                             unsigned char* __restrict__ colpart) {
  const int t = threadIdx.x;
  const int b = blockIdx.x;
  const int u0 = b * 8;
  uint32_t cs[16];
#pragma unroll
  for (int k = 0; k < 16; ++k) cs[k] = 0;
#pragma unroll
  for (int rb = 0; rb < 2; ++rb) {
    f32x4 a[4][4];
    // phase 1: 16 independent float4 loads (4 rows x 64B/thread)
#pragma unroll
    for (int r = 0; r < 4; ++r) {
      const f32x4* p = reinterpret_cast<const f32x4*>(A + (size_t)(u0 + rb * 4 + r) * NN + t * 16);
#pragma unroll
      for (int c = 0; c < 4; ++c) a[r][c] = p[c];
    }
    // phase 2: consume
#pragma unroll
    for (int r = 0; r < 4; ++r) {
      uint32_t m = 0;
#pragma unroll
      for (int c = 0; c < 4; ++c)
#pragma unroll
        for (int j = 0; j < 4; ++j) m |= (a[r][c][j] >= TH ? 1u : 0u) << (c * 4 + j);
      bits16[(size_t)(u0 + rb * 4 + r) * 256 + t] = (unsigned short)m;
#pragma unroll
      for (int k = 0; k < 16; ++k) cs[k] += (m >> k) & 1u;
    }
  }
  uint4 pk;
  pk.x = cs[0]  | (cs[1]  << 8) | (cs[2]  << 16) | (cs[3]  << 24);
  pk.y = cs[4]  | (cs[5]  << 8) | (cs[6]  << 16) | (cs[7]  << 24);
  pk.z = cs[8]  | (cs[9]  << 8) | (cs[10] << 16) | (cs[11] << 24);
  pk.w = cs[12] | (cs[13] << 8) | (cs[14] << 16) | (cs[15] << 24);
  *reinterpret_cast<uint4*>(colpart + (size_t)b * 4096 + t * 16) = pk;
}

// ---- fused: row degrees (popcount of bits), col degrees (reduce colpart),
// ---- rsqrt, and W1/W2 transpose->bf16. Grid = 16 + 64 + 16 = 96 blocks. --
__global__ __launch_bounds__(256) void k_cnt(const unsigned short* __restrict__ bits16,
                                             const unsigned char* __restrict__ colpart,
                                             const float* __restrict__ W1,
                                             const float* __restrict__ W2,
                                             float* __restrict__ oi,
                                             float* __restrict__ ii,
                                             unsigned short* __restrict__ WTb,
                                             unsigned short* __restrict__ W2Tb) {
  __shared__ uint32_t cl[4][64];
  const int t = threadIdx.x;
  const int b = blockIdx.x;
  if (b < 16) {
    // row degree: popcount over the row's 512B of mask bits
    const int u = b * 256 + t;
    const uint4* p = reinterpret_cast<const uint4*>(bits16 + (size_t)u * 256);
    uint32_t s = 0;
#pragma unroll
    for (int j = 0; j < 32; ++j) {
      uint4 x = p[j];
      s += __popc(x.x) + __popc(x.y) + __popc(x.z) + __popc(x.w);
    }
    oi[u] = rsqrtf((float)(s + 1u));          // +1 self loop, always >= 1
  } else if (b < 80) {
    // col degree: 64 v's per block; 4 wave-slices over the 512 block-partials
    const int vbase = (b - 16) * 64;
    const int vl = t & 63, sl = t >> 6;
    uint32_t s = 0;
#pragma unroll 4
    for (int bb = sl * 128; bb < sl * 128 + 128; ++bb)
      s += colpart[(size_t)bb * 4096 + vbase + vl];
    cl[sl][vl] = s;
    __syncthreads();
    if (t < 64) {
      uint32_t tot = cl[0][t] + cl[1][t] + cl[2][t] + cl[3][t];
      ii[vbase + t] = rsqrtf((float)(tot + 1u));
    }
  } else {
    // W^T -> bf16 for both layers
    const int base = (b - 80) * 4096 + t * 16;
#pragma unroll
    for (int e = 0; e < 16; ++e) {
      int idx = base + e;
      int d = idx >> 8, k = idx & 255;
      WTb[idx]  = f2bf(W1[k * 256 + d]);
      W2Tb[idx] = f2bf(W2[k * 256 + d]);
    }
  }
}

// ---- hW = (H * oi[:,None]) @ W  -> hWb [u][d] bf16 and hWbT [d][u] bf16 --
__global__ __launch_bounds__(256) void k_hw(const float* __restrict__ H,
                                            const float* __restrict__ oi,
                                            const unsigned short* __restrict__ WTb,
                                            unsigned short* __restrict__ hWb,
                                            unsigned short* __restrict__ hWbT) {
  __shared__ unsigned short lt[64][260];
  const int t = threadIdx.x;
  const int lane = t & 63, w = t >> 6;
  const int l15 = lane & 15, l4 = lane >> 4;
  const int u0 = blockIdx.x * 64;
  const f32x4 z = {0.f, 0.f, 0.f, 0.f};
  f32x4 acc[4][4];
#pragma unroll
  for (int i = 0; i < 4; ++i)
#pragma unroll
    for (int j = 0; j < 4; ++j) acc[i][j] = z;
  float oiv[4];
#pragma unroll
  for (int i = 0; i < 4; ++i) oiv[i] = oi[u0 + i * 16 + l15];

  for (int ks = 0; ks < 8; ++ks) {
    const int k0 = ks * 32;
    s16x8 af[4];
#pragma unroll
    for (int i = 0; i < 4; ++i) {
      const f32x4* pa = reinterpret_cast<const f32x4*>(H + (size_t)(u0 + i * 16 + l15) * DD + k0 + l4 * 8);
      f32x4 a0 = pa[0], a1 = pa[1];
#pragma unroll
      for (int j = 0; j < 4; ++j) {
        af[i][j]     = (short)f2bf(a0[j] * oiv[i]);
        af[i][j + 4] = (short)f2bf(a1[j] * oiv[i]);
      }
    }
#pragma unroll
    for (int jn = 0; jn < 4; ++jn) {
      const int d = w * 64 + jn * 16 + l15;
      s16x8 bf = *reinterpret_cast<const s16x8*>(WTb + (size_t)d * DD + k0 + l4 * 8);
#pragma unroll
      for (int i = 0; i < 4; ++i)
        acc[i][jn] = __builtin_amdgcn_mfma_f32_16x16x32_bf16(af[i], bf, acc[i][jn], 0, 0, 0);
    }
  }
  // epilogue: hWb direct, hWbT via LDS transpose
#pragma unroll
  for (int i = 0; i < 4; ++i)
#pragma unroll
    for (int jn = 0; jn < 4; ++jn) {
      const int d = w * 64 + jn * 16 + l15;
#pragma unroll
      for (int r = 0; r < 4; ++r) {
        const int ul = i * 16 + l4 * 4 + r;      // C/D: row=(l>>4)*4+reg, col=l&15
        unsigned short hv = f2bf(acc[i][jn][r]);
        hWb[(size_t)(u0 + ul) * DD + d] = hv;
        lt[ul][d] = hv;
      }
    }
  __syncthreads();
#pragma unroll
  for (int c = 0; c < 8; ++c) {                  // thread t owns hWbT row d=t
    uint4 val;
    val.x = (uint32_t)lt[c*8+0][t] | ((uint32_t)lt[c*8+1][t] << 16);
    val.y = (uint32_t)lt[c*8+2][t] | ((uint32_t)lt[c*8+3][t] << 16);
    val.z = (uint32_t)lt[c*8+4][t] | ((uint32_t)lt[c*8+5][t] << 16);
    val.w = (uint32_t)lt[c*8+6][t] | ((uint32_t)lt[c*8+7][t] << 16);
    *reinterpret_cast<uint4*>(hWbT + (size_t)t * NN + u0 + c * 8) = val;
  }
}

// ---- partial[sk][v][d] = sum_{u in chunk} mask[u][v] * hW[u][d] ----------
__global__ __launch_bounds__(256) void k_spmm(const uint64_t* __restrict__ bits,
                                              const unsigned short* __restrict__ hWbT,
                                              float* __restrict__ part) {
  const int t = threadIdx.x;
  const int lane = t & 63, w = t >> 6;
  const int l15 = lane & 15, l4 = lane >> 4;
  const int bv = blockIdx.x;          // word column == v-tile (64 v per word)
  const int sk = blockIdx.y;
  const int kbase = sk * 1024;
  const f32x4 z = {0.f, 0.f, 0.f, 0.f};
  f32x4 acc[4][4];
#pragma unroll
  for (int i = 0; i < 4; ++i)
#pragma unroll
    for (int j = 0; j < 4; ++j) acc[i][j] = z;

  uint2 wa[8]; s16x8 ba[4];
  uint2 wb[8]; s16x8 bb[4];

  auto loadw = [&](uint2* wv, s16x8* bv8, int k) {
#pragma unroll
    for (int j = 0; j < 8; ++j)
      wv[j] = *reinterpret_cast<const uint2*>(bits + (size_t)(k + l4 * 8 + j) * 64 + bv);
#pragma unroll
    for (int jn = 0; jn < 4; ++jn)
      bv8[jn] = *reinterpret_cast<const s16x8*>(hWbT + (size_t)(w * 64 + jn * 16 + l15) * NN + k + l4 * 8);
  };
  auto comp = [&](const uint2* wv, const s16x8* bv8) {
    s16x8 af[4];
#pragma unroll
    for (int i = 0; i < 4; ++i) {                // A-frag: m = i*16+l15, k = l4*8+j
      const int sh = (i & 1) * 16 + l15;
#pragma unroll
      for (int j = 0; j < 8; ++j) {
        uint32_t h = (i < 2) ? wv[j].x : wv[j].y;
        af[i][j] = (short)((((h >> sh) & 1u) != 0u) ? 0x3F80 : 0);
      }
    }
#pragma unroll
    for (int i = 0; i < 4; ++i)
#pragma unroll
      for (int jn = 0; jn < 4; ++jn)
        acc[i][jn] = __builtin_amdgcn_mfma_f32_16x16x32_bf16(af[i], bv8[jn], acc[i][jn], 0, 0, 0);
  };

  loadw(wa, ba, kbase);
#pragma unroll 1
  for (int it = 0; it < 16; ++it) {
    loadw(wb, bb, kbase + it * 64 + 32);
    comp(wa, ba);
    loadw(wa, ba, kbase + it * 64 + 64);   // last iter reads in-ws garbage, unused
    comp(wb, bb);
  }
  float* __restrict__ P = part + (size_t)sk * NN * DD;
#pragma unroll
  for (int i = 0; i < 4; ++i)
#pragma unroll
    for (int jn = 0; jn < 4; ++jn) {
      const int d = w * 64 + jn * 16 + l15;
#pragma unroll
      for (int r = 0; r < 4; ++r) {
        const int v = bv * 64 + i * 16 + l4 * 4 + r;
        P[(size_t)v * DD + d] = acc[i][jn][r];
      }
    }
}

// ---- combine: out = relu((sum_k partials + hW_self) * ii[v] + b[d]) ------
__global__ __launch_bounds__(256) void k_comb(const float* __restrict__ part,
                                              const unsigned short* __restrict__ hWb,
                                              const float* __restrict__ ii,
                                              const float* __restrict__ bias,
                                              float* __restrict__ out) {
  const int idx4 = blockIdx.x * 256 + threadIdx.x;   // 0..262143 (float4 units)
  const f32x4* p = reinterpret_cast<const f32x4*>(part);
  f32x4 s = p[idx4];
  s += p[idx4 + 262144];
  s += p[idx4 + 2 * 262144];
  s += p[idx4 + 3 * 262144];
  u16x4 hs = *reinterpret_cast<const u16x4*>(hWb + (size_t)idx4 * 4);
  const int v = idx4 >> 6;
  const int dbase = (idx4 & 63) * 4;
  const float iiv = ii[v];
  f32x4 o;
#pragma unroll
  for (int e = 0; e < 4; ++e) {
    float val = (s[e] + bf2f(hs[e])) * iiv + bias[dbase + e];
    o[e] = fmaxf(val, 0.f);
  }
  reinterpret_cast<f32x4*>(out)[idx4] = o;
}

extern "C" void kernel_launch(void* const* d_in, const int* in_sizes, int n_in,
                              void* d_out, int out_size, void* d_ws, size_t ws_size,
                              hipStream_t stream) {
  const float* A    = (const float*)d_in[0];
  const float* feat = (const float*)d_in[1];
  const float* W1   = (const float*)d_in[2];
  const float* b1   = (const float*)d_in[3];
  const float* W2   = (const float*)d_in[4];
  const float* b2   = (const float*)d_in[5];
  float* out = (float*)d_out;
  char* ws = (char*)d_ws;

  unsigned short* bits16 = (unsigned short*)ws;                 // 2 MiB
  unsigned short* hWbT   = (unsigned short*)(ws + (2u  << 20)); // 2 MiB
  unsigned short* hWb    = (unsigned short*)(ws + (4u  << 20)); // 2 MiB
  float*          part   = (float*)(ws + (6u  << 20));          // 16 MiB
  unsigned char*  colpart= (unsigned char*)part;                // aliases dead part region
  unsigned short* WTb    = (unsigned short*)(ws + (22u << 20));            // 128 KiB
  unsigned short* W2Tb   = (unsigned short*)(ws + (22u << 20) + (128u << 10));
  float*          oi     = (float*)(ws + (22u << 20) + (256u << 10));
  float*          ii     = oi + NN;
  // total ws use ~22.3 MiB

  k_deg<<<512, 256, 0, stream>>>(A, bits16, colpart);
  k_cnt<<<96, 256, 0, stream>>>(bits16, colpart, W1, W2, oi, ii, WTb, W2Tb);

  const uint64_t* bits = (const uint64_t*)bits16;

  // layer 1
  k_hw<<<64, 256, 0, stream>>>(feat, oi, WTb, hWb, hWbT);
  k_spmm<<<dim3(64, 4), 256, 0, stream>>>(bits, hWbT, part);
  k_comb<<<1024, 256, 0, stream>>>(part, hWb, ii, b1, out);

  // layer 2
  k_hw<<<64, 256, 0, stream>>>(out, oi, W2Tb, hWb, hWbT);
  k_spmm<<<dim3(64, 4), 256, 0, stream>>>(bits, hWbT, part);
  k_comb<<<1024, 256, 0, stream>>>(part, hWb, ii, b2, out + (size_t)NN * DD);
}